// Round 2
// baseline (56757.629 us; speedup 1.0000x reference)
//
#include <hip/hip_runtime.h>
#include <hip/hip_fp16.h>

#define TT 1024
#define BB 64
#define HH 256
#define NQ 4          // blocks per batch group (h-slices)
#define SL 64         // HH / NQ
#define NTH 1024
#define NW 16         // waves per block

// ---- workspace byte layout ----
#define UAM_BYTES (1ull * TT * BB * HH * 2)          // fp16 uam[T][B][H]  33.55 MB
#define STW_BYTES (1ull * BB * HH * 4)               // st[B][H]
#define EP_BYTES  (1ull * BB * NQ * TT * 4)          // eparts[B][NQ][T]
#define BAR_BYTES ((BB * 32 + 32) * 4)               // counters + broken flag
#define WS_NEED   (UAM_BYTES + STW_BYTES + EP_BYTES + BAR_BYTES)   // ~34.9 MB

__device__ __forceinline__ float tanh_fast(float xx) {
  // tanh(x) = 1 - 2/(1+exp(2x)); stable both tails
  float e = __expf(2.0f * xx);
  return 1.0f - 2.0f * __builtin_amdgcn_rcpf(e + 1.0f);
}

// agent-scope (sc1, coherent-point) element accessors for cross-block data
__device__ __forceinline__ float ld_cg(const float* p) {
  return __hip_atomic_load(p, __ATOMIC_RELAXED, __HIP_MEMORY_SCOPE_AGENT);
}
__device__ __forceinline__ void st_cg(float* p, float v) {
  __hip_atomic_store(p, v, __ATOMIC_RELAXED, __HIP_MEMORY_SCOPE_AGENT);
}

__device__ __forceinline__ void bar_post(int* cnt) {
  __syncthreads();   // drains all threads' stores (vmcnt 0) before the flag add
  if (threadIdx.x == 0)
    __hip_atomic_fetch_add(cnt, 1, __ATOMIC_RELEASE, __HIP_MEMORY_SCOPE_AGENT);
}
__device__ __forceinline__ void bar_wait(int* cnt, int* broken, int target) {
  if (threadIdx.x == 0) {
    long it = 0;
    while (__hip_atomic_load(cnt, __ATOMIC_RELAXED, __HIP_MEMORY_SCOPE_AGENT) < target) {
      if (__hip_atomic_load(broken, __ATOMIC_RELAXED, __HIP_MEMORY_SCOPE_AGENT)) break;
      if (++it > 5000000) {  // liveness valve (~1 s); never hit in correct runs
        __hip_atomic_store(broken, 1, __ATOMIC_RELAXED, __HIP_MEMORY_SCOPE_AGENT);
        break;
      }
    }
  }
  __syncthreads();
}

#define RED16(a) { a += __shfl_xor(a, 1); a += __shfl_xor(a, 2); \
                   a += __shfl_xor(a, 4); a += __shfl_xor(a, 8); }

extern "C" __global__ void __launch_bounds__(NTH, 4)
memrnn_scan(const float* __restrict__ x, const float* __restrict__ U_w,
            const float* __restrict__ U_b, const float* __restrict__ V_w,
            const float* __restrict__ Ua_w, const float* __restrict__ Va_w,
            const float* __restrict__ vvec, float* __restrict__ out,
            char* __restrict__ wsb)
{
  const int blk  = blockIdx.x;
  const int b    = blk >> 2;      // batch group
  const int q    = blk & 3;       // h-slice
  const int tid  = threadIdx.x;
  const int lane = tid & 63;
  const int wav  = tid >> 6;
  const int r    = tid >> 4;      // gemv row 0..63 (16 threads each)
  const int c    = tid & 15;      // i-chunk id (i = j*16 + c)
  const int gr   = q * SL + r;

  __half* uam = (__half*)wsb;                                   // block-private slices
  float*  stw = (float*)(wsb + UAM_BYTES);                      // cross-block (sc1)
  float*  ep  = (float*)(wsb + UAM_BYTES + STW_BYTES);          // cross-block (sc1)
  int* barbase = (int*)(wsb + UAM_BYTES + STW_BYTES + EP_BYTES);
  int* bar    = barbase + b * 32;
  int* broken = barbase + BB * 32;

  // persistent register weights (row-chunks, 16 strided cols per thread)
  float wV[16], wUa[16], wVa[16], wU[16];
#pragma unroll
  for (int j = 0; j < 16; ++j) {
    const int i = j * 16 + c;
    wV[j]  = V_w [gr * HH + i];
    wUa[j] = Ua_w[gr * HH + i];
    wVa[j] = Va_w[gr * HH + i];
    wU[j]  = U_w [gr * HH + i];
  }
  const float bias = U_b[gr];
  const float v_l  = vvec[q * SL + lane];

  __shared__ float s_vec[HH];       // st staging
  __shared__ float s_x[HH];         // x row staging
  __shared__ float s_h[HH];         // full-h staging
  __shared__ float s_a[SL];         // a = Va*st, own rows
  __shared__ float s_e[TT];         // combined e scores
  __shared__ float s_red[NW * SL];
  __shared__ float s_d[NW];

  int tgt = 0;

  // ================= prologue: t = 0 =================
  if (tid < HH) s_x[tid] = x[(size_t)b * HH + tid];
  __syncthreads();
  {
    float acc = 0.f;
#pragma unroll
    for (int j = 0; j < 16; ++j) acc += wU[j] * s_x[j * 16 + c];
    RED16(acc);
    if (c == 0) {
      const float s0 = acc + bias;                 // st0 (pre-tanh)
      st_cg(&stw[b * HH + gr], s0);
      st_cg(&out[(size_t)b * HH + gr], tanh_fast(s0));   // mem[0]
    }
  }
  bar_post(bar); tgt += NQ; bar_wait(bar, broken, tgt);
  if (tid < HH) {
    s_vec[tid] = ld_cg(&stw[b * HH + tid]);        // full st0
    s_h[tid]   = ld_cg(&out[(size_t)b * HH + tid]); // full h0
  }
  __syncthreads();
  { // a for t=1
    float acc = 0.f;
#pragma unroll
    for (int j = 0; j < 16; ++j) acc += wVa[j] * s_vec[j * 16 + c];
    RED16(acc);
    if (c == 0) s_a[r] = acc;
  }
  { // uam[0] own rows (private, plain stores)
    float acc = 0.f;
#pragma unroll
    for (int j = 0; j < 16; ++j) acc += wUa[j] * s_h[j * 16 + c];
    RED16(acc);
    if (c == 0) uam[(size_t)b * HH + gr] = __float2half(acc);
  }
  __syncthreads();

  // ================= main loop =================
  for (int t = 1; t < TT; ++t) {
    // ---- P1: e-partials over own slice, all t2 < t ----
    {
      const float a_l = s_a[lane];
      const __half* uq = uam + (size_t)b * HH + q * SL + lane;
      float* epg = ep + ((size_t)b * NQ + q) * TT;
#pragma unroll 4
      for (int t2 = wav; t2 < t; t2 += NW) {
        const float u = __half2float(uq[(size_t)t2 * (BB * HH)]);
        float p = v_l * tanh_fast(a_l + u);
        p += __shfl_xor(p, 1);  p += __shfl_xor(p, 2);  p += __shfl_xor(p, 4);
        p += __shfl_xor(p, 8);  p += __shfl_xor(p, 16); p += __shfl_xor(p, 32);
        if (lane == 0) st_cg(&epg[t2], p);
      }
    }
    bar_post(bar); tgt += NQ; bar_wait(bar, broken, tgt);          // alpha

    // ---- P2: stage+combine e into LDS, softmax-weighted sum of mem ----
    if (tid < t) {
      const float* e0 = ep + (size_t)b * NQ * TT;
      s_e[tid] = ld_cg(&e0[tid]) + ld_cg(&e0[TT + tid]) +
                 ld_cg(&e0[2 * TT + tid]) + ld_cg(&e0[3 * TT + tid]);
    }
    __syncthreads();
    {
      float num = 0.f, den = 0.f;
      const float* memq = out + (size_t)b * HH + q * SL + lane;
#pragma unroll 8
      for (int t2 = wav; t2 < t; t2 += NW) {
        const float w = __expf(s_e[t2]);           // |e| <= ~13, no max pass needed
        den += w;
        num += w * memq[(size_t)t2 * (BB * HH)];
      }
      s_red[wav * SL + lane] = num;
      if (lane == 0) s_d[wav] = den;
    }
    __syncthreads();
    if (wav == 0) {
      float nt = 0.f, dt = 0.f;
#pragma unroll
      for (int w2 = 0; w2 < NW; ++w2) { nt += s_red[w2 * SL + lane]; dt += s_d[w2]; }
      const float ct = nt / dt;
      const float* memq = out + (size_t)b * HH + q * SL + lane;
      const float stn = memq[(size_t)(t - 1) * (BB * HH)] + ct;   // last_h + ct
      st_cg(&stw[b * HH + q * SL + lane], stn);
    }
    bar_post(bar); tgt += NQ; bar_wait(bar, broken, tgt);          // beta

    // ---- P3: h = tanh(Ux[t] + V*st_new), own rows ----
    if (tid < HH) {
      s_vec[tid] = ld_cg(&stw[b * HH + tid]);      // full st_{t+1}
      s_x[tid]   = x[((size_t)t * BB + b) * HH + tid];
    }
    __syncthreads();
    {
      float acc = 0.f;
#pragma unroll
      for (int j = 0; j < 16; ++j) {
        const int i = j * 16 + c;
        acc += wV[j] * s_vec[i] + wU[j] * s_x[i];
      }
      RED16(acc);
      if (c == 0) st_cg(&out[((size_t)t * BB + b) * HH + gr], tanh_fast(acc + bias));
    }
    if (t < TT - 1) {
      bar_post(bar);                                               // gamma post
      { // Va gemv for step t+1 (s_vec holds st_{t+1}) — hides gamma wait
        float acc = 0.f;
#pragma unroll
        for (int j = 0; j < 16; ++j) acc += wVa[j] * s_vec[j * 16 + c];
        RED16(acc);
        if (c == 0) s_a[r] = acc;
      }
      tgt += NQ; bar_wait(bar, broken, tgt);                       // gamma wait
      if (tid < HH) s_h[tid] = ld_cg(&out[((size_t)t * BB + b) * HH + tid]);
      __syncthreads();
      { // uam[t] own rows (private)
        float acc = 0.f;
#pragma unroll
        for (int j = 0; j < 16; ++j) acc += wUa[j] * s_h[j * 16 + c];
        RED16(acc);
        if (c == 0) uam[((size_t)t * BB + b) * HH + gr] = __float2half(acc);
      }
      __syncthreads();
    }
  }

  // diagnostic: deadlock valve triggered -> unmistakable absmax signature
  if (tid == 0 &&
      __hip_atomic_load(broken, __ATOMIC_RELAXED, __HIP_MEMORY_SCOPE_AGENT))
    st_cg(&out[0], 1.0e6f);
}

__global__ void ws_sentinel(float* out) { out[0] = 2.0e6f; }

extern "C" void kernel_launch(void* const* d_in, const int* in_sizes, int n_in,
                              void* d_out, int out_size, void* d_ws, size_t ws_size,
                              hipStream_t stream) {
  const float* x    = (const float*)d_in[0];
  const float* U_w  = (const float*)d_in[1];
  const float* U_b  = (const float*)d_in[2];
  const float* V_w  = (const float*)d_in[3];
  const float* Ua_w = (const float*)d_in[4];
  const float* Va_w = (const float*)d_in[5];
  const float* v    = (const float*)d_in[6];
  float* out = (float*)d_out;

  if (ws_size < WS_NEED) {  // diagnosable failure signature (absmax ~2e6)
    ws_sentinel<<<1, 1, 0, stream>>>(out);
    return;
  }
  // zero barrier counters + broken flag each launch (graph-capturable)
  hipMemsetAsync((char*)d_ws + (UAM_BYTES + STW_BYTES + EP_BYTES), 0, BAR_BYTES, stream);
  memrnn_scan<<<dim3(BB * NQ), dim3(NTH), 0, stream>>>(
      x, U_w, U_b, V_w, Ua_w, Va_w, v, out, (char*)d_ws);
}

// Round 3
// 21165.749 us; speedup vs baseline: 2.6816x; 2.6816x over previous
//
#include <hip/hip_runtime.h>
#include <hip/hip_fp16.h>

#define TT 1024
#define BB 64
#define HH 256
#define NQ 4          // blocks per batch group (h-slices)
#define SL 64         // HH / NQ
#define NTH 1024
#define NW 16         // waves per block

// ---- workspace byte layout ----
#define MIR_BYTES (256ull * TT * SL * 2)   // fp16 mem mirror [blk][T][64]  32 MB, block-private
#define STW_BYTES (1ull * BB * HH * 4)     // st[B][H]        cross-block (sc1)
#define EP_BYTES  (1ull * BB * NQ * TT * 4)// e-partials       cross-block (sc1)
#define BAR_BYTES ((BB * 32 + 32) * 4)
#define WS_NEED   (MIR_BYTES + STW_BYTES + EP_BYTES + BAR_BYTES)   // ~34.6 MB

__device__ __forceinline__ float tanh_fast(float xx) {
  float e = __expf(2.0f * xx);
  return 1.0f - 2.0f * __builtin_amdgcn_rcpf(e + 1.0f);
}

// agent-scope element accessors for cross-block data (bypass local caches)
__device__ __forceinline__ float ld_cg(const float* p) {
  return __hip_atomic_load(p, __ATOMIC_RELAXED, __HIP_MEMORY_SCOPE_AGENT);
}
__device__ __forceinline__ void st_cg(float* p, float v) {
  __hip_atomic_store(p, v, __ATOMIC_RELAXED, __HIP_MEMORY_SCOPE_AGENT);
}

__device__ __forceinline__ void bar_post(int* cnt) {
  __syncthreads();   // drains vmcnt(0): all this block's sc1 stores are acked
  if (threadIdx.x == 0)
    __hip_atomic_fetch_add(cnt, 1, __ATOMIC_RELEASE, __HIP_MEMORY_SCOPE_AGENT);
}
__device__ __forceinline__ void bar_wait(int* cnt, int* broken, int target) {
  if (threadIdx.x == 0) {
    long it = 0;
    while (__hip_atomic_load(cnt, __ATOMIC_RELAXED, __HIP_MEMORY_SCOPE_AGENT) < target) {
      if (__hip_atomic_load(broken, __ATOMIC_RELAXED, __HIP_MEMORY_SCOPE_AGENT)) break;
      if (++it > 5000000) {
        __hip_atomic_store(broken, 1, __ATOMIC_RELAXED, __HIP_MEMORY_SCOPE_AGENT);
        break;
      }
    }
  }
  __syncthreads();
}

#define RED16(a) { a += __shfl_xor(a, 1); a += __shfl_xor(a, 2); \
                   a += __shfl_xor(a, 4); a += __shfl_xor(a, 8); }

extern "C" __global__ void __launch_bounds__(NTH, 4)
memrnn_scan(const float* __restrict__ x, const float* __restrict__ U_w,
            const float* __restrict__ U_b, const float* __restrict__ V_w,
            const float* __restrict__ Ua_w, const float* __restrict__ Va_w,
            const float* __restrict__ vvec, float* __restrict__ out,
            char* __restrict__ wsb)
{
  const int blk  = blockIdx.x;
  const int b    = blk & 63;      // batch group: 4 blocks {b, b+64, b+128, b+192} -> same XCD
  const int q    = blk >> 6;      // h-slice
  const int tid  = threadIdx.x;
  const int lane = tid & 63;
  const int wav  = tid >> 6;
  const int r    = tid >> 4;      // gemv row 0..63 (16 threads each)
  const int c    = tid & 15;      // col-chunk id (i = j*16 + c)
  const int gr   = q * SL + r;

  __half* mir = (__half*)wsb + (size_t)blk * TT * SL;            // private fp16 mem mirror
  float*  stw = (float*)(wsb + MIR_BYTES);                       // cross-block (sc1)
  float*  ep  = (float*)(wsb + MIR_BYTES + STW_BYTES);           // cross-block (sc1)
  int* barbase = (int*)(wsb + MIR_BYTES + STW_BYTES + EP_BYTES);
  int* bar    = barbase + b * 32;
  int* broken = barbase + BB * 32;

  // persistent register weights (own 64 rows, 16 strided cols per thread)
  float wV[16], wUa[16], wVa[16], wU[16];
#pragma unroll
  for (int j = 0; j < 16; ++j) {
    const int i = j * 16 + c;
    wV[j]  = V_w [gr * HH + i];
    wUa[j] = Ua_w[gr * HH + i];
    wVa[j] = Va_w[gr * HH + i];
    wU[j]  = U_w [gr * HH + i];
  }
  const float bias = U_b[gr];

  // ---- LDS: uam history (fp16, swizzled col = h ^ (t2&63)) + staging ----
  __shared__ __half s_uam[TT * SL];   // 128 KB
  __shared__ float2 s_av[SL];         // .x = (Va*st)[h], .y = v[h]  (own slice)
  __shared__ float  s_vec[HH];        // full st staging
  __shared__ float  s_x[HH];          // x row staging
  __shared__ float  s_h[HH];          // full h staging
  __shared__ float  s_e[TT];          // combined e scores
  __shared__ float  s_red[NW * SL];
  __shared__ float  s_d[NW];

  int tgt = 0;

  // ================= prologue: t = 0 =================
  if (tid < HH) s_x[tid] = x[(size_t)b * HH + tid];
  __syncthreads();
  {
    float acc = 0.f;
#pragma unroll
    for (int j = 0; j < 16; ++j) acc += wU[j] * s_x[j * 16 + c];
    RED16(acc);
    if (c == 0) st_cg(&stw[b * HH + gr], acc + bias);   // st0 (pre-tanh)
  }
  bar_post(bar); tgt += NQ; bar_wait(bar, broken, tgt);
  if (tid < HH) {
    const float sv = ld_cg(&stw[b * HH + tid]);
    s_vec[tid] = sv;
    s_h[tid]   = tanh_fast(sv);       // full h0, computed locally (V(hidden)=0 at t=0)
  }
  __syncthreads();
  if (tid < SL) {                      // own slice of h0 -> out + mirror
    const float h0 = s_h[q * SL + tid];
    st_cg(&out[(size_t)b * HH + q * SL + tid], h0);
    mir[tid] = __float2half(h0);
  }
  {
    float acca = 0.f, accu = 0.f;
#pragma unroll
    for (int j = 0; j < 16; ++j) {
      const int i = j * 16 + c;
      acca += wVa[j] * s_vec[i];
      accu += wUa[j] * s_h[i];
    }
    RED16(acca); RED16(accu);
    if (c == 0) {
      s_av[r] = make_float2(acca, vvec[gr]);
      s_uam[r] = __float2half(accu);   // row 0, swizzle (r ^ 0)
    }
  }
  __syncthreads();

  // ================= main loop =================
  for (int t = 1; t < TT; ++t) {
    // ---- P1 (LDS-only, transposed): lane = t2, serial over uniform h ----
    {
      float* epg = ep + ((size_t)(b * NQ + q)) * TT;
      for (int ci = wav; ci * SL < t; ci += NW) {
        const int t2 = ci * SL + lane;          // tail lanes may exceed t (masked)
        const int rb = t2 * SL;
        float p = 0.f;
#pragma unroll 8
        for (int h = 0; h < SL; ++h) {
          const float2 av = s_av[h];            // uniform broadcast
          const float u = __half2float(s_uam[rb + (h ^ lane)]);
          p = fmaf(av.y, tanh_fast(av.x + u), p);
        }
        if (t2 < t) st_cg(&epg[t2], p);          // coalesced 64-lane store
      }
    }
    bar_post(bar); tgt += NQ; bar_wait(bar, broken, tgt);          // alpha

    // ---- P2: combine e (sc1), softmax-weighted sum over private fp16 mirror ----
    if (tid < t) {
      const float* e0 = ep + (size_t)b * NQ * TT + tid;
      s_e[tid] = ld_cg(e0) + ld_cg(e0 + TT) + ld_cg(e0 + 2 * TT) + ld_cg(e0 + 3 * TT);
    }
    __syncthreads();
    {
      float num = 0.f, den = 0.f;
#pragma unroll 4
      for (int t2 = wav; t2 < t; t2 += NW) {
        const float w = __expf(s_e[t2]);        // |e| <= ~13: no max pass needed
        den += w;
        num = fmaf(w, __half2float(mir[(size_t)t2 * SL + lane]), num);
      }
      s_red[wav * SL + lane] = num;
      if (lane == 0) s_d[wav] = den;
    }
    __syncthreads();
    if (wav == 0) {
      float nt = 0.f, dt = 0.f;
#pragma unroll
      for (int w2 = 0; w2 < NW; ++w2) { nt += s_red[w2 * SL + lane]; dt += s_d[w2]; }
      const float ct  = nt / dt;
      const float stn = __half2float(mir[(size_t)(t - 1) * SL + lane]) + ct; // last_h + ct
      st_cg(&stw[b * HH + q * SL + lane], stn);
    }
    float xv = 0.f;
    bar_post(bar); tgt += NQ;                                      // beta post
    if (tid < HH) xv = x[((size_t)t * BB + b) * HH + tid];          // overlap with wait
    bar_wait(bar, broken, tgt);                                    // beta wait

    // ---- P3: h = tanh(Ux + V*st_new) own rows; also a = Va*st_new for next P1 ----
    if (tid < HH) {
      s_x[tid]   = xv;
      s_vec[tid] = ld_cg(&stw[b * HH + tid]);
    }
    __syncthreads();
    {
      float acc = 0.f, acca = 0.f;
#pragma unroll
      for (int j = 0; j < 16; ++j) {
        const int i = j * 16 + c;
        const float sv = s_vec[i];
        acc  += wV[j] * sv + wU[j] * s_x[i];
        acca += wVa[j] * sv;
      }
      RED16(acc); RED16(acca);
      if (c == 0) {
        const float hv = tanh_fast(acc + bias);
        st_cg(&out[((size_t)t * BB + b) * HH + gr], hv);
        mir[(size_t)t * SL + r] = __float2half(hv);
        s_av[r].x = acca;
      }
    }
    if (t < TT - 1) {
      bar_post(bar); tgt += NQ; bar_wait(bar, broken, tgt);        // gamma
      // ---- P4: uam[t] = Ua * h_full -> LDS history ----
      if (tid < HH) s_h[tid] = ld_cg(&out[((size_t)t * BB + b) * HH + tid]);
      __syncthreads();
      {
        float acc = 0.f;
#pragma unroll
        for (int j = 0; j < 16; ++j) acc += wUa[j] * s_h[j * 16 + c];
        RED16(acc);
        if (c == 0) s_uam[t * SL + (r ^ (t & 63))] = __float2half(acc);
      }
      __syncthreads();
    }
  }

  if (tid == 0 &&
      __hip_atomic_load(broken, __ATOMIC_RELAXED, __HIP_MEMORY_SCOPE_AGENT))
    st_cg(&out[0], 1.0e6f);   // deadlock signature
}

__global__ void ws_sentinel(float* out) { out[0] = 2.0e6f; }

extern "C" void kernel_launch(void* const* d_in, const int* in_sizes, int n_in,
                              void* d_out, int out_size, void* d_ws, size_t ws_size,
                              hipStream_t stream) {
  const float* x    = (const float*)d_in[0];
  const float* U_w  = (const float*)d_in[1];
  const float* U_b  = (const float*)d_in[2];
  const float* V_w  = (const float*)d_in[3];
  const float* Ua_w = (const float*)d_in[4];
  const float* Va_w = (const float*)d_in[5];
  const float* v    = (const float*)d_in[6];
  float* out = (float*)d_out;

  if (ws_size < WS_NEED) {            // diagnosable failure (absmax ~2e6)
    ws_sentinel<<<1, 1, 0, stream>>>(out);
    return;
  }
  hipMemsetAsync((char*)d_ws + (MIR_BYTES + STW_BYTES + EP_BYTES), 0, BAR_BYTES, stream);
  memrnn_scan<<<dim3(BB * NQ), dim3(NTH), 0, stream>>>(
      x, U_w, U_b, V_w, Ua_w, Va_w, v, out, (char*)d_ws);
}